// Round 1
// baseline (101.671 us; speedup 1.0000x reference)
//
#include <hip/hip_runtime.h>
#include <math.h>

// Problem constants (from reference setup_inputs)
#define B 64
#define N 128            // logits H=W
#define M 136            // targets H=W
#define S1 9             // shift rows
#define S2 9             // shift cols
#define S 81
#define NPIX (N*N)       // 16384
#define MPIX (M*M)       // 18496
#define CENTER 40        // (4)*9 + 4

__device__ __forceinline__ float softplus_f(float x) {
    // max(x,0) + log1p(exp(-|x|))  == stable BCE logits-only term
    return fmaxf(x, 0.0f) + log1pf(expf(-fabsf(x)));
}

// ---------------- Kernel 1: P[b] = sum softplus(x[b]) ----------------
__global__ __launch_bounds__(256) void k_softplus(const float* __restrict__ x,
                                                  float* __restrict__ P) {
    int b = blockIdx.x;
    const float4* xb = (const float4*)(x + (size_t)b * NPIX);
    float s = 0.0f;
    for (int q = threadIdx.x; q < NPIX / 4; q += 256) {
        float4 v = xb[q];
        s += softplus_f(v.x) + softplus_f(v.y) + softplus_f(v.z) + softplus_f(v.w);
    }
    #pragma unroll
    for (int m = 32; m; m >>= 1) s += __shfl_xor(s, m, 64);
    __shared__ float ps[4];
    if ((threadIdx.x & 63) == 0) ps[threadIdx.x >> 6] = s;
    __syncthreads();
    if (threadIdx.x == 0) P[b] = (ps[0] + ps[1]) + (ps[2] + ps[3]);
}

// ---------------- Kernel 2: D2[b][s][h] = partial cross-correlation ----------------
// grid.x = 18 (i*2 + h), grid.y = B. Each block: rows r0..r0+63 of x[b],
// shift row i, all 9 shift cols.
__global__ __launch_bounds__(256) void k_corr(const float* __restrict__ x,
                                              const float* __restrict__ y,
                                              float* __restrict__ D2) {
    int b = blockIdx.y;
    int i = blockIdx.x >> 1;
    int h = blockIdx.x & 1;
    int r0 = h * 64;

    __shared__ float ylds[64 * M];          // 34816 B
    // stage y rows (i+r0) .. (i+r0+63), all 136 cols
    {
        const float4* ysrc = (const float4*)(y + (size_t)b * MPIX + (i + r0) * M);
        float4* ydst = (float4*)ylds;
        for (int q = threadIdx.x; q < 64 * (M / 4); q += 256) ydst[q] = ysrc[q];
    }
    __syncthreads();

    float acc[9];
    #pragma unroll
    for (int j = 0; j < 9; ++j) acc[j] = 0.0f;

    const float4* xb = (const float4*)(x + (size_t)b * NPIX + r0 * N);
    // 2048 quads in this half; thread handles 8 of them
    #pragma unroll
    for (int k = 0; k < 8; ++k) {
        int q = threadIdx.x + 256 * k;
        int r = q >> 5;              // 0..63 (32 quads per 128-wide row)
        int c = (q & 31) * 4;        // 0..124
        float4 xv = xb[q];
        const float* yrow = ylds + r * M + c;
        float4 y0 = *(const float4*)(yrow);
        float4 y1 = *(const float4*)(yrow + 4);
        float4 y2 = *(const float4*)(yrow + 8);
        float ya[12] = { y0.x, y0.y, y0.z, y0.w,
                         y1.x, y1.y, y1.z, y1.w,
                         y2.x, y2.y, y2.z, y2.w };
        #pragma unroll
        for (int j = 0; j < 9; ++j) {
            acc[j] += xv.x * ya[j] + xv.y * ya[j + 1]
                    + xv.z * ya[j + 2] + xv.w * ya[j + 3];
        }
    }

    // block reduce 9 sums
    #pragma unroll
    for (int j = 0; j < 9; ++j) {
        #pragma unroll
        for (int m = 32; m; m >>= 1) acc[j] += __shfl_xor(acc[j], m, 64);
    }
    __shared__ float part[4][9];
    int w = threadIdx.x >> 6;
    if ((threadIdx.x & 63) == 0) {
        #pragma unroll
        for (int j = 0; j < 9; ++j) part[w][j] = acc[j];
    }
    __syncthreads();
    if (threadIdx.x < 9) {
        int j = threadIdx.x;
        float s = (part[0][j] + part[1][j]) + (part[2][j] + part[3][j]);
        D2[((size_t)b * S + (i * 9 + j)) * 2 + h] = s;
    }
}

// ---------------- Kernel 3: argmin + tiebreak + total loss + shifts ----------------
__global__ __launch_bounds__(64) void k_argmin(const float* __restrict__ P,
                                               const float* __restrict__ D2,
                                               float* __restrict__ out,
                                               int* __restrict__ minij) {
    int b = threadIdx.x;   // 64 threads, one wave
    float p = P[b];
    const float inv = 1.0f / (float)NPIX;
    float best = INFINITY;
    float errc = INFINITY;
    int bi = 0;
    for (int s = 0; s < S; ++s) {
        float d = D2[((size_t)b * S + s) * 2] + D2[((size_t)b * S + s) * 2 + 1];
        float e = (p - d) * inv;
        if (s == CENTER) errc = e;
        if (e < best) { best = e; bi = s; }   // strict < keeps first min
    }
    if (errc == best) bi = CENTER;            // prefer center on exact tie
    minij[b] = bi;
    out[1 + B * NPIX + b]      = (float)(bi / S2);   // row_shifts
    out[1 + B * NPIX + B + b]  = (float)(bi % S2);   // col_shifts
    float t = best;
    #pragma unroll
    for (int m = 32; m; m >>= 1) t += __shfl_xor(t, m, 64);
    if (b == 0) out[0] = t;                   // total_loss
}

// ---------------- Kernel 4: gather adjusted_labels ----------------
__global__ __launch_bounds__(256) void k_gather(const float* __restrict__ y,
                                                const int* __restrict__ minij,
                                                float* __restrict__ out) {
    int idx = blockIdx.x * 256 + threadIdx.x;   // 0 .. B*NPIX-1
    int b  = idx >> 14;
    int rc = idx & (NPIX - 1);
    int r = rc >> 7;
    int c = rc & (N - 1);
    int ij = minij[b];                           // uniform per block
    int i = ij / S2;
    int j = ij % S2;
    out[1 + idx] = y[(size_t)b * MPIX + (r + i) * M + (c + j)];
}

extern "C" void kernel_launch(void* const* d_in, const int* in_sizes, int n_in,
                              void* d_out, int out_size, void* d_ws, size_t ws_size,
                              hipStream_t stream) {
    const float* x = (const float*)d_in[0];   // logits (64,1,128,128)
    const float* y = (const float*)d_in[1];   // targets (64,1,136,136)
    float* out = (float*)d_out;               // [1 + 64*16384 + 64 + 64]

    float* wsF   = (float*)d_ws;
    float* P     = wsF;                        // 64 floats
    float* D2    = wsF + B;                    // 64*81*2 floats
    int*   minij = (int*)(wsF + B + B * S * 2); // 64 ints

    k_softplus<<<B, 256, 0, stream>>>(x, P);
    k_corr<<<dim3(18, B), 256, 0, stream>>>(x, y, D2);
    k_argmin<<<1, 64, 0, stream>>>(P, D2, out, minij);
    k_gather<<<(B * NPIX) / 256, 256, 0, stream>>>(y, minij, out);
}

// Round 2
// 85.302 us; speedup vs baseline: 1.1919x; 1.1919x over previous
//
#include <hip/hip_runtime.h>
#include <math.h>

// Problem constants (from reference setup_inputs)
#define B 64
#define N 128            // logits H=W
#define M 136            // targets H=W
#define S2 9             // shift cols (and rows)
#define S 81
#define NPIX (N*N)       // 16384
#define MPIX (M*M)       // 18496
#define CENTER 40        // 4*9 + 4

// Fast softplus for the shift-independent BCE term: max(x,0)+log1p(exp(-|x|)).
// exp arg <= 0 so t in (0,1], 1+t in (1,2] -> native log is accurate there.
// This term does NOT affect the argmin (argmin_s(P - D_s) == argmax_s D_s).
__device__ __forceinline__ float softplus_f(float x) {
    float t = __expf(-fabsf(x));
    return fmaxf(x, 0.0f) + __logf(1.0f + t);
}

// ---------------- Kernel A: cross-correlation + fused softplus sum ----------------
// grid.x = 18 (i*2 + h), grid.y = B. Each block: rows r0..r0+63 of x[b],
// shift row i, all 9 shift cols. Blocks with i==0 additionally accumulate
// the softplus sum over their x half into P2[b*2+h].
__global__ __launch_bounds__(256) void k_corr(const float* __restrict__ x,
                                              const float* __restrict__ y,
                                              float* __restrict__ D2,
                                              float* __restrict__ P2) {
    int b = blockIdx.y;
    int i = blockIdx.x >> 1;
    int h = blockIdx.x & 1;
    int r0 = h * 64;
    const bool do_sp = (i == 0);      // block-uniform

    __shared__ float ylds[64 * M];    // 34816 B
    {
        const float4* ysrc = (const float4*)(y + (size_t)b * MPIX + (i + r0) * M);
        float4* ydst = (float4*)ylds;
        for (int q = threadIdx.x; q < 64 * (M / 4); q += 256) ydst[q] = ysrc[q];
    }
    __syncthreads();

    float acc[9];
    #pragma unroll
    for (int j = 0; j < 9; ++j) acc[j] = 0.0f;
    float sp = 0.0f;

    const float4* xb = (const float4*)(x + (size_t)b * NPIX + r0 * N);
    #pragma unroll
    for (int k = 0; k < 8; ++k) {
        int q = threadIdx.x + 256 * k;
        int r = q >> 5;              // 0..63 (32 quads per 128-wide row)
        int c = (q & 31) * 4;        // 0..124
        float4 xv = xb[q];
        const float* yrow = ylds + r * M + c;
        float4 y0 = *(const float4*)(yrow);
        float4 y1 = *(const float4*)(yrow + 4);
        float4 y2 = *(const float4*)(yrow + 8);
        float ya[12] = { y0.x, y0.y, y0.z, y0.w,
                         y1.x, y1.y, y1.z, y1.w,
                         y2.x, y2.y, y2.z, y2.w };
        #pragma unroll
        for (int j = 0; j < 9; ++j) {
            acc[j] += xv.x * ya[j] + xv.y * ya[j + 1]
                    + xv.z * ya[j + 2] + xv.w * ya[j + 3];
        }
        if (do_sp) {
            sp += softplus_f(xv.x) + softplus_f(xv.y)
                + softplus_f(xv.z) + softplus_f(xv.w);
        }
    }

    // block-reduce the 9 correlation sums
    #pragma unroll
    for (int j = 0; j < 9; ++j) {
        #pragma unroll
        for (int m = 32; m; m >>= 1) acc[j] += __shfl_xor(acc[j], m, 64);
    }
    __shared__ float part[4][9];
    __shared__ float spart[4];
    int w = threadIdx.x >> 6;
    if ((threadIdx.x & 63) == 0) {
        #pragma unroll
        for (int j = 0; j < 9; ++j) part[w][j] = acc[j];
    }
    if (do_sp) {
        #pragma unroll
        for (int m = 32; m; m >>= 1) sp += __shfl_xor(sp, m, 64);
        if ((threadIdx.x & 63) == 0) spart[w] = sp;
    }
    __syncthreads();
    if (threadIdx.x < 9) {
        int j = threadIdx.x;
        float s = (part[0][j] + part[1][j]) + (part[2][j] + part[3][j]);
        D2[((size_t)b * S + (i * 9 + j)) * 2 + h] = s;
    }
    if (do_sp && threadIdx.x == 9) {
        P2[b * 2 + h] = (spart[0] + spart[1]) + (spart[2] + spart[3]);
    }
}

// ---------------- Kernel B: per-block argmin recompute + gather (+ outputs) -------
// Blocks 0..4095: gather adjusted_labels for their 256 pixels, recomputing the
// batch argmax_s D locally. Block 4096: total_loss + shifts.
__global__ __launch_bounds__(256) void k_gather(const float* __restrict__ y,
                                                const float* __restrict__ D2,
                                                const float* __restrict__ P2,
                                                float* __restrict__ out) {
    if (blockIdx.x < 4096) {
        int b = blockIdx.x >> 6;
        __shared__ float dsum[S];
        __shared__ int sij;
        if (threadIdx.x < S) {
            dsum[threadIdx.x] = D2[((size_t)b * S + threadIdx.x) * 2]
                              + D2[((size_t)b * S + threadIdx.x) * 2 + 1];
        }
        __syncthreads();
        if (threadIdx.x == 0) {
            float best = -INFINITY; int bi = 0;
            for (int s = 0; s < S; ++s) {
                float d = dsum[s];
                if (d > best) { best = d; bi = s; }   // strict > keeps first
            }
            if (dsum[CENTER] == best) bi = CENTER;    // center tiebreak
            sij = bi;
        }
        __syncthreads();
        int ij = sij;
        int i = ij / S2, j = ij % S2;
        int idx = blockIdx.x * 256 + threadIdx.x;
        int rc = idx & (NPIX - 1);
        int r = rc >> 7;
        int c = rc & (N - 1);
        out[1 + idx] = y[(size_t)b * MPIX + (r + i) * M + (c + j)];
    } else {
        // outputs block: one wave, one lane per batch
        int b = threadIdx.x;
        if (b < B) {
            float p = P2[2 * b] + P2[2 * b + 1];
            float best = -INFINITY; int bi = 0;
            for (int s = 0; s < S; ++s) {
                float d = D2[((size_t)b * S + s) * 2] + D2[((size_t)b * S + s) * 2 + 1];
                if (d > best) { best = d; bi = s; }
            }
            {
                float dc = D2[((size_t)b * S + CENTER) * 2] + D2[((size_t)b * S + CENTER) * 2 + 1];
                if (dc == best) bi = CENTER;
            }
            out[1 + B * NPIX + b]     = (float)(bi / S2);   // row_shifts
            out[1 + B * NPIX + B + b] = (float)(bi % S2);   // col_shifts
            float t = (p - best) * (1.0f / (float)NPIX);
            #pragma unroll
            for (int m = 32; m; m >>= 1) t += __shfl_xor(t, m, 64);
            if (b == 0) out[0] = t;                          // total_loss
        }
    }
}

extern "C" void kernel_launch(void* const* d_in, const int* in_sizes, int n_in,
                              void* d_out, int out_size, void* d_ws, size_t ws_size,
                              hipStream_t stream) {
    const float* x = (const float*)d_in[0];   // logits (64,1,128,128)
    const float* y = (const float*)d_in[1];   // targets (64,1,136,136)
    float* out = (float*)d_out;               // [1 + 64*16384 + 64 + 64]

    float* wsF = (float*)d_ws;
    float* D2  = wsF;                  // 64*81*2 floats
    float* P2  = wsF + B * S * 2;      // 64*2 floats

    k_corr<<<dim3(18, B), 256, 0, stream>>>(x, y, D2, P2);
    k_gather<<<4097, 256, 0, stream>>>(y, D2, P2, out);
}